// Round 1
// baseline (471.089 us; speedup 1.0000x reference)
//
#include <hip/hip_runtime.h>
#include <cstdint>
#include <cmath>

// Problem constants: N=100000, IN=64, HID=32, R=3, B=2, E=1600000, G=256, 4 layers
// CSR build v2: direct atomic degree-count -> two-level scan -> atomic scatter.
// (within-node edge order is arbitrary; sums are order-insensitive within fp32 tol,
//  and the previous version's order was already race-dependent)

// ---------------- degree count: deg[dst[e]]++ ----------------
__global__ __launch_bounds__(256) void deg_count_kernel(
    const int* __restrict__ dst, int* __restrict__ deg, int E)
{
    int tid = blockIdx.x * 256 + threadIdx.x;
    int e0 = tid * 4;
    if (e0 + 4 <= E) {
        int4 d = ((const int4*)dst)[tid];
        atomicAdd(&deg[d.x], 1);
        atomicAdd(&deg[d.y], 1);
        atomicAdd(&deg[d.z], 1);
        atomicAdd(&deg[d.w], 1);
    } else {
        for (int e = e0; e < E; ++e) atomicAdd(&deg[dst[e]], 1);
    }
}

// ---------------- two-level exclusive scan over N ----------------
// scan1: per-block (1024 nodes) local exclusive scan + block sums
__global__ __launch_bounds__(1024) void scan1_kernel(
    const int* __restrict__ deg, int* __restrict__ rp,
    int* __restrict__ bsum, int N)
{
    __shared__ int s[1024];
    int t = threadIdx.x;
    int n = blockIdx.x * 1024 + t;
    int v = (n < N) ? deg[n] : 0;
    s[t] = v; __syncthreads();
    for (int off = 1; off < 1024; off <<= 1) {
        int u = (t >= off) ? s[t - off] : 0;
        __syncthreads();
        s[t] += u;
        __syncthreads();
    }
    if (n < N) rp[n] = s[t] - v;
    if (t == 1023) bsum[blockIdx.x] = s[1023];
}

// scan2: single block exclusive scan of the (<=128) block sums, in place
__global__ __launch_bounds__(128) void scan2_kernel(int* __restrict__ bsum, int NS)
{
    __shared__ int s[128];
    int t = threadIdx.x;
    int v = (t < NS) ? bsum[t] : 0;
    s[t] = v; __syncthreads();
    for (int off = 1; off < 128; off <<= 1) {
        int u = (t >= off) ? s[t - off] : 0;
        __syncthreads();
        s[t] += u;
        __syncthreads();
    }
    if (t < NS) bsum[t] = s[t] - v;
}

// scan3: add block bases; rp = final row base, cur = running cursor (same value)
__global__ __launch_bounds__(256) void scan3_kernel(
    int* __restrict__ rp, int* __restrict__ cur, const int* __restrict__ bsum, int N)
{
    int n = blockIdx.x * 256 + threadIdx.x;
    if (n < N) {
        int b = rp[n] + bsum[n >> 10];
        rp[n] = b;
        cur[n] = b;
    }
}

// ---------------- scatter: one pass, atomic slot claim ----------------
// after this kernel, cur[n] == row end (rp[n] + deg[n])
__global__ __launch_bounds__(256) void scatter_kernel(
    const int* __restrict__ src, const int* __restrict__ dst,
    const int* __restrict__ et, int* __restrict__ cur,
    unsigned* __restrict__ eidx, int E)
{
    int tid = blockIdx.x * 256 + threadIdx.x;
    int e0 = tid * 4;
    if (e0 + 4 <= E) {
        int4 s4 = ((const int4*)src)[tid];
        int4 d4 = ((const int4*)dst)[tid];
        int4 t4 = ((const int4*)et)[tid];
        int p;
        p = atomicAdd(&cur[d4.x], 1); eidx[p] = (unsigned)s4.x | ((unsigned)t4.x << 17);
        p = atomicAdd(&cur[d4.y], 1); eidx[p] = (unsigned)s4.y | ((unsigned)t4.y << 17);
        p = atomicAdd(&cur[d4.z], 1); eidx[p] = (unsigned)s4.z | ((unsigned)t4.z << 17);
        p = atomicAdd(&cur[d4.w], 1); eidx[p] = (unsigned)s4.w | ((unsigned)t4.w << 17);
    } else {
        for (int e = e0; e < E; ++e) {
            int p = atomicAdd(&cur[dst[e]], 1);
            eidx[p] = (unsigned)src[e] | ((unsigned)et[e] << 17);
        }
    }
}

// ---------------- dense layer-1 v3: weights-only LDS, x via L1 broadcast ------
// builds W on the fly (prep_w1 fused): sW[m] = sum_b comp[m,b]*basis1[b] (m<3), loop1 (m=3)
// hrel[r][n][:] = x@W[r]; agg[n][:] = x@loop1 + bias
__global__ __launch_bounds__(256, 4) void dense_kernel(
    const float* __restrict__ x,
    const float* __restrict__ basis1,   // [2][64][32]
    const float* __restrict__ loop1,    // [64][32]
    const float* __restrict__ w_comp,   // [4][3][2]; layer-0 slice used
    const float* __restrict__ bias_l,   // [32]
    float* __restrict__ hrel,           // [3][N][32]
    float* __restrict__ agg,            // [N][32]
    int N)
{
    __shared__ float sW[4 * 2048];      // [4][64][32], 32 KB (only LDS use)
    const int tid = threadIdx.x;
    for (int i = tid; i < 4 * 2048; i += 256) {
        int m = i >> 11, io = i & 2047;
        float v;
        if (m < 3) v = w_comp[m * 2] * basis1[io] + w_comp[m * 2 + 1] * basis1[2048 + io];
        else       v = loop1[io];
        sW[i] = v;
    }
    __syncthreads();

    const int m  = tid >> 6;       // wave id = which matrix (0..2 rel, 3 loop)
    const int l  = tid & 63;
    const int ow = l & 7;          // output quad: cols ow*4 .. ow*4+3
    const int ng = l >> 3;         // node sub-id: nodes j*8 + ng, j=0..7
    const int nb = blockIdx.x * 64;

    // per-j row pointers, clamped for the partial last block (stores are guarded)
    const float* xr[8];
    #pragma unroll
    for (int j = 0; j < 8; ++j) {
        int gn = nb + j * 8 + ng;
        if (gn > N - 1) gn = N - 1;
        xr[j] = x + (size_t)gn * 64;
    }

    float acc[8][4];
    #pragma unroll
    for (int j = 0; j < 8; ++j)
        #pragma unroll
        for (int k = 0; k < 4; ++k) acc[j][k] = 0.0f;

    const float* wb = &sW[m * 2048 + ow * 4];
    #pragma unroll 2
    for (int i = 0; i < 64; i += 4) {
        float4 wv0 = *(const float4*)(wb + (i + 0) * 32);
        float4 wv1 = *(const float4*)(wb + (i + 1) * 32);
        float4 wv2 = *(const float4*)(wb + (i + 2) * 32);
        float4 wv3 = *(const float4*)(wb + (i + 3) * 32);
        #pragma unroll
        for (int j = 0; j < 8; ++j) {
            float4 hv = *(const float4*)(xr[j] + i);
            acc[j][0] += hv.x * wv0.x + hv.y * wv1.x + hv.z * wv2.x + hv.w * wv3.x;
            acc[j][1] += hv.x * wv0.y + hv.y * wv1.y + hv.z * wv2.y + hv.w * wv3.y;
            acc[j][2] += hv.x * wv0.z + hv.y * wv1.z + hv.z * wv2.z + hv.w * wv3.z;
            acc[j][3] += hv.x * wv0.w + hv.y * wv1.w + hv.z * wv2.w + hv.w * wv3.w;
        }
    }

    if (m < 3) {
        #pragma unroll
        for (int j = 0; j < 8; ++j) {
            int n = nb + j * 8 + ng;
            if (n < N)
                *(float4*)&hrel[((size_t)m * N + n) * 32 + ow * 4] =
                    make_float4(acc[j][0], acc[j][1], acc[j][2], acc[j][3]);
        }
    } else {
        float4 bb = *(const float4*)&bias_l[ow * 4];
        #pragma unroll
        for (int j = 0; j < 8; ++j) {
            int n = nb + j * 8 + ng;
            if (n < N)
                *(float4*)&agg[(size_t)n * 32 + ow * 4] =
                    make_float4(acc[j][0] + bb.x, acc[j][1] + bb.y,
                                acc[j][2] + bb.z, acc[j][3] + bb.w);
        }
    }
}

// ------- layer-1 gather: feat[n][j] = tanh(agg[n][j] + sum hrel[et][src][j]) --
// cnt = rend[n] - rp[n]  (rend = post-scatter cursor = row end)
__global__ __launch_bounds__(256) void gather1_kernel(
    const unsigned* __restrict__ eidx, const int* __restrict__ rp,
    const int* __restrict__ rend, const float* __restrict__ hrel,
    const float* __restrict__ agg, float* __restrict__ feat, int N)
{
    int tid = blockIdx.x * 256 + threadIdx.x;
    int n = tid >> 3;
    if (n >= N) return;
    int c = (tid & 7) << 2;
    int base = rp[n], cnt = rend[n] - base;
    const float4 bv = *(const float4*)&agg[(size_t)n * 32 + c];
    float a0[4] = {bv.x, bv.y, bv.z, bv.w};
    float a1[4] = {0, 0, 0, 0}, a2[4] = {0, 0, 0, 0}, a3[4] = {0, 0, 0, 0};
    int k = 0;
    for (; k + 4 <= cnt; k += 4) {
        unsigned p0 = eidx[base + k + 0], p1 = eidx[base + k + 1];
        unsigned p2 = eidx[base + k + 2], p3 = eidx[base + k + 3];
        float4 v0 = *(const float4*)&hrel[(((size_t)((p0 >> 17) & 3)) * N + (p0 & 0x1FFFF)) * 32 + c];
        float4 v1 = *(const float4*)&hrel[(((size_t)((p1 >> 17) & 3)) * N + (p1 & 0x1FFFF)) * 32 + c];
        float4 v2 = *(const float4*)&hrel[(((size_t)((p2 >> 17) & 3)) * N + (p2 & 0x1FFFF)) * 32 + c];
        float4 v3 = *(const float4*)&hrel[(((size_t)((p3 >> 17) & 3)) * N + (p3 & 0x1FFFF)) * 32 + c];
        a0[0] += v0.x; a0[1] += v0.y; a0[2] += v0.z; a0[3] += v0.w;
        a1[0] += v1.x; a1[1] += v1.y; a1[2] += v1.z; a1[3] += v1.w;
        a2[0] += v2.x; a2[1] += v2.y; a2[2] += v2.z; a2[3] += v2.w;
        a3[0] += v3.x; a3[1] += v3.y; a3[2] += v3.z; a3[3] += v3.w;
    }
    for (; k < cnt; ++k) {
        unsigned p = eidx[base + k];
        float4 v = *(const float4*)&hrel[(((size_t)((p >> 17) & 3)) * N + (p & 0x1FFFF)) * 32 + c];
        a0[0] += v.x; a0[1] += v.y; a0[2] += v.z; a0[3] += v.w;
    }
    float r0 = a0[0] + a1[0] + a2[0] + a3[0];
    float r1 = a0[1] + a1[1] + a2[1] + a3[1];
    float r2 = a0[2] + a1[2] + a2[2] + a3[2];
    float r3 = a0[3] + a1[3] + a2[3] + a3[3];
    float4* out = (float4*)&feat[(size_t)n * 128 + c];
    *out = make_float4(tanhf(r0), tanhf(r1), tanhf(r2), tanhf(r3));
}

// ------- fused layers 2-4: T_b[n] = sum_e comp[r,b]*h[src]; out = tanh(...) ---
__global__ __launch_bounds__(256) void fused_layer_kernel(
    const unsigned* __restrict__ eidx, const int* __restrict__ rp,
    const int* __restrict__ rend,
    const float* __restrict__ basis_b,  // [2][32][32]
    const float* __restrict__ loop_w,   // [32][32]
    const float* __restrict__ bias_l,   // [32]
    const float* __restrict__ comp,     // [3][2]
    const float* __restrict__ feat_in,  // feat + (l-1)*32, stride 128
    float* __restrict__ feat_out,       // feat + l*32,     stride 128
    int N)
{
    __shared__ float sB0[1024], sB1[1024], sL[1024];
    __shared__ float sT0[32 * 36], sT1[32 * 36], sH[32 * 36];
    const int tid = threadIdx.x;
    for (int i = tid; i < 1024; i += 256) {
        sB0[i] = basis_b[i];
        sB1[i] = basis_b[1024 + i];
        sL[i]  = loop_w[i];
    }
    const float cc0r0 = comp[0], cc1r0 = comp[1];
    const float cc0r1 = comp[2], cc1r1 = comp[3];
    const float cc0r2 = comp[4], cc1r2 = comp[5];

    const int nn = tid >> 3, cg = (tid & 7) << 2;
    const int n = blockIdx.x * 32 + nn;

    float4 h4 = *(const float4*)&feat_in[(size_t)n * 128 + cg];
    *(float4*)&sH[nn * 36 + cg] = h4;

    const int base = rp[n], cnt = rend[n] - base;
    float t0a[4] = {0,0,0,0}, t1a[4] = {0,0,0,0};
    float t0b[4] = {0,0,0,0}, t1b[4] = {0,0,0,0};
    int k = 0;
    for (; k + 4 <= cnt; k += 4) {
        unsigned p0 = eidx[base + k + 0], p1 = eidx[base + k + 1];
        unsigned p2 = eidx[base + k + 2], p3 = eidx[base + k + 3];
        int r0 = (p0 >> 17) & 3, r1 = (p1 >> 17) & 3;
        int r2 = (p2 >> 17) & 3, r3 = (p3 >> 17) & 3;
        float4 v0 = *(const float4*)&feat_in[(size_t)(p0 & 0x1FFFF) * 128 + cg];
        float4 v1 = *(const float4*)&feat_in[(size_t)(p1 & 0x1FFFF) * 128 + cg];
        float4 v2 = *(const float4*)&feat_in[(size_t)(p2 & 0x1FFFF) * 128 + cg];
        float4 v3 = *(const float4*)&feat_in[(size_t)(p3 & 0x1FFFF) * 128 + cg];
        float c00 = r0 == 0 ? cc0r0 : (r0 == 1 ? cc0r1 : cc0r2);
        float c10 = r0 == 0 ? cc1r0 : (r0 == 1 ? cc1r1 : cc1r2);
        float c01 = r1 == 0 ? cc0r0 : (r1 == 1 ? cc0r1 : cc0r2);
        float c11 = r1 == 0 ? cc1r0 : (r1 == 1 ? cc1r1 : cc1r2);
        float c02 = r2 == 0 ? cc0r0 : (r2 == 1 ? cc0r1 : cc0r2);
        float c12 = r2 == 0 ? cc1r0 : (r2 == 1 ? cc1r1 : cc1r2);
        float c03 = r3 == 0 ? cc0r0 : (r3 == 1 ? cc0r1 : cc0r2);
        float c13 = r3 == 0 ? cc1r0 : (r3 == 1 ? cc1r1 : cc1r2);
        t0a[0] += c00*v0.x; t0a[1] += c00*v0.y; t0a[2] += c00*v0.z; t0a[3] += c00*v0.w;
        t1a[0] += c10*v0.x; t1a[1] += c10*v0.y; t1a[2] += c10*v0.z; t1a[3] += c10*v0.w;
        t0b[0] += c01*v1.x; t0b[1] += c01*v1.y; t0b[2] += c01*v1.z; t0b[3] += c01*v1.w;
        t1b[0] += c11*v1.x; t1b[1] += c11*v1.y; t1b[2] += c11*v1.z; t1b[3] += c11*v1.w;
        t0a[0] += c02*v2.x; t0a[1] += c02*v2.y; t0a[2] += c02*v2.z; t0a[3] += c02*v2.w;
        t1a[0] += c12*v2.x; t1a[1] += c12*v2.y; t1a[2] += c12*v2.z; t1a[3] += c12*v2.w;
        t0b[0] += c03*v3.x; t0b[1] += c03*v3.y; t0b[2] += c03*v3.z; t0b[3] += c03*v3.w;
        t1b[0] += c13*v3.x; t1b[1] += c13*v3.y; t1b[2] += c13*v3.z; t1b[3] += c13*v3.w;
    }
    for (; k < cnt; ++k) {
        unsigned p = eidx[base + k];
        int r = (p >> 17) & 3;
        float4 v = *(const float4*)&feat_in[(size_t)(p & 0x1FFFF) * 128 + cg];
        float c0 = r == 0 ? cc0r0 : (r == 1 ? cc0r1 : cc0r2);
        float c1 = r == 0 ? cc1r0 : (r == 1 ? cc1r1 : cc1r2);
        t0a[0] += c0*v.x; t0a[1] += c0*v.y; t0a[2] += c0*v.z; t0a[3] += c0*v.w;
        t1a[0] += c1*v.x; t1a[1] += c1*v.y; t1a[2] += c1*v.z; t1a[3] += c1*v.w;
    }
    *(float4*)&sT0[nn * 36 + cg] = make_float4(t0a[0]+t0b[0], t0a[1]+t0b[1],
                                               t0a[2]+t0b[2], t0a[3]+t0b[3]);
    *(float4*)&sT1[nn * 36 + cg] = make_float4(t1a[0]+t1b[0], t1a[1]+t1b[1],
                                               t1a[2]+t1b[2], t1a[3]+t1b[3]);
    __syncthreads();

    float4 bb = *(const float4*)&bias_l[cg];
    float a[4] = {bb.x, bb.y, bb.z, bb.w};
    #pragma unroll 8
    for (int kk = 0; kk < 32; ++kk) {
        float p0 = sT0[nn * 36 + kk];
        float p1 = sT1[nn * 36 + kk];
        float hh = sH[nn * 36 + kk];
        float4 b0 = *(const float4*)&sB0[kk * 32 + cg];
        float4 b1 = *(const float4*)&sB1[kk * 32 + cg];
        float4 lw = *(const float4*)&sL[kk * 32 + cg];
        a[0] += p0 * b0.x + p1 * b1.x + hh * lw.x;
        a[1] += p0 * b0.y + p1 * b1.y + hh * lw.y;
        a[2] += p0 * b0.z + p1 * b1.z + hh * lw.z;
        a[3] += p0 * b0.w + p1 * b1.w + hh * lw.w;
    }
    *(float4*)&feat_out[(size_t)n * 128 + cg] =
        make_float4(tanhf(a[0]), tanhf(a[1]), tanhf(a[2]), tanhf(a[3]));
}

// ------- pooling: node-chunk blocks, run-accumulate, atomic flush ----------
__global__ __launch_bounds__(256) void pool_kernel(
    const float* __restrict__ feat, const int* __restrict__ gid,
    float* __restrict__ pooled, float* __restrict__ cntArr, int N)
{
    int chunk0 = blockIdx.x * 128;
    int ch = threadIdx.x & 127, half = threadIdx.x >> 7;
    int n = chunk0 + half;
    int lim = chunk0 + 128; if (lim > N) lim = N;
    if (n >= lim) return;
    int cur = gid[n];
    float acc = 0.0f; int cc = 0;
    for (; n < lim; n += 2) {
        int g = gid[n];
        if (g != cur) {
            atomicAdd(&pooled[(size_t)cur * 128 + ch], acc);
            if (ch == 0) atomicAdd(&cntArr[cur], (float)cc);
            acc = 0.0f; cc = 0; cur = g;
        }
        acc += feat[(size_t)n * 128 + ch];
        ++cc;
    }
    atomicAdd(&pooled[(size_t)cur * 128 + ch], acc);
    if (ch == 0) atomicAdd(&cntArr[cur], (float)cc);
}

// ---------------- final MLP (divides pooled sums by counts) -------------------
__global__ __launch_bounds__(64) void mlp_kernel(
    const float* __restrict__ pooled, const float* __restrict__ cntArr,
    const float* __restrict__ w1, const float* __restrict__ b1,
    const float* __restrict__ w2, const float* __restrict__ b2,
    float* __restrict__ out)
{
    int g = blockIdx.x;
    int t = threadIdx.x;  // 64
    float inv = 1.0f / fmaxf(cntArr[g], 1.0f);
    float acc = b1[t];
    #pragma unroll 8
    for (int k = 0; k < 128; ++k)
        acc += pooled[(size_t)g * 128 + k] * inv * w1[k * 64 + t];
    float h = fmaxf(acc, 0.0f);
    float p = h * w2[t];
    #pragma unroll
    for (int off = 32; off > 0; off >>= 1) p += __shfl_down(p, off, 64);
    if (t == 0) out[g] = 1.0f / (1.0f + expf(-(p + b2[0])));
}

extern "C" void kernel_launch(void* const* d_in, const int* in_sizes, int n_in,
                              void* d_out, int out_size, void* d_ws, size_t ws_size,
                              hipStream_t stream)
{
    const float* x       = (const float*)d_in[0];
    const float* basis1  = (const float*)d_in[1];
    const float* basis_r = (const float*)d_in[2];
    const float* w_comp  = (const float*)d_in[3];
    const float* loop1   = (const float*)d_in[4];
    const float* loop_r  = (const float*)d_in[5];
    const float* bias    = (const float*)d_in[6];
    const float* lin1_w  = (const float*)d_in[7];
    const float* lin1_b  = (const float*)d_in[8];
    const float* lin2_w  = (const float*)d_in[9];
    const float* lin2_b  = (const float*)d_in[10];
    const int*   src     = (const int*)d_in[11];
    const int*   dst     = (const int*)d_in[12];
    const int*   etype   = (const int*)d_in[13];
    const int*   gid     = (const int*)d_in[14];

    const int N = in_sizes[0] / 64;
    const int E = in_sizes[11];
    const int G = out_size;  // 256
    const int NSB = (N + 1023) >> 10;       // scan super-blocks (98)

    // workspace layout (words):
    // hrel[3*N*32] | agg[N*32] | feat[N*128] | pooled[G*128] | cntArr[G]
    // | rend[N] (deg -> cursor -> row end) | rp[N] | bsum[NSB] | eidx2[E]
    float* ws      = (float*)d_ws;
    float* hrel    = ws;                          // 3*N*32
    float* agg     = hrel + (size_t)3 * N * 32;   // N*32
    float* feat    = agg + (size_t)N * 32;        // N*128
    float* pooled  = feat + (size_t)N * 128;      // G*128
    float* cntArr  = pooled + (size_t)G * 128;    // G
    int*   rend    = (int*)(cntArr + G);          // N (zeroed; deg counts, then cursor)
    int*   rp      = rend + N;                    // N
    int*   bsum    = rp + N;                      // NSB (<=128)
    unsigned* eidx2 = (unsigned*)(bsum + 128);    // E

    // zero pooled + cntArr + rend(deg) in one shot (contiguous)
    hipMemsetAsync(pooled, 0, ((size_t)G * 128 + G + N) * sizeof(float), stream);

    // CSR build: degree count -> two-level scan -> atomic scatter
    deg_count_kernel<<<(E / 4 + 255) / 256, 256, 0, stream>>>(dst, rend, E);
    scan1_kernel<<<NSB, 1024, 0, stream>>>(rend, rp, bsum, N);
    scan2_kernel<<<1, 128, 0, stream>>>(bsum, NSB);
    scan3_kernel<<<(N + 255) / 256, 256, 0, stream>>>(rp, rend, bsum, N);
    scatter_kernel<<<(E / 4 + 255) / 256, 256, 0, stream>>>(src, dst, etype, rend, eidx2, E);
    // rend now holds row ends: cnt(n) = rend[n] - rp[n]

    // layer 1: dense (weight-prep fused; x via L1) + register gather (fused tanh)
    dense_kernel<<<(N + 63) / 64, 256, 0, stream>>>(x, basis1, loop1, w_comp, bias, hrel, agg, N);
    gather1_kernel<<<(N * 8 + 255) / 256, 256, 0, stream>>>(eidx2, rp, rend, hrel, agg, feat, N);

    // layers 2-4: fused comp-weighted gather + in-LDS matmuls + tanh
    for (int l = 1; l < 4; ++l) {
        fused_layer_kernel<<<(N + 31) / 32, 256, 0, stream>>>(
            eidx2, rp, rend,
            basis_r + (size_t)(l - 1) * 2048,
            loop_r + (size_t)(l - 1) * 1024,
            bias + l * 32,
            w_comp + l * 6,
            feat + (l - 1) * 32,
            feat + l * 32,
            N);
    }

    pool_kernel<<<(N + 127) / 128, 256, 0, stream>>>(feat, gid, pooled, cntArr, N);
    mlp_kernel<<<G, 64, 0, stream>>>(pooled, cntArr, lin1_w, lin1_b, lin2_w, lin2_b, (float*)d_out);
}

// Round 2
// 375.595 us; speedup vs baseline: 1.2542x; 1.2542x over previous
//
#include <hip/hip_runtime.h>
#include <cstdint>
#include <cmath>

// Problem constants: N=100000, IN=64, HID=32, R=3, B=2, E=1600000, G=256, 4 layers
// CSR build v3: bucketed (write-locality) build with 4x more blocks than v1.
// Buckets: bucket = dst >> 7 (128 nodes), NB = ceil(N/128) = 782
#define DLO_BITS 7
#define DLO_MASK 127
#define SCAT_Q 2048   // edges per bscatter/count block (was 8192; occupancy fix)

// ---------------- bucket count ----------------
__global__ __launch_bounds__(256) void count_kernel(
    const int* __restrict__ dst, int* __restrict__ bcnt, int E, int NB)
{
    __shared__ int cnt[1024];
    for (int i = threadIdx.x; i < NB; i += 256) cnt[i] = 0;
    __syncthreads();
    int base = blockIdx.x * SCAT_Q;
    #pragma unroll
    for (int i = 0; i < SCAT_Q / 256; ++i) {
        int e = base + i * 256 + threadIdx.x;
        if (e < E) atomicAdd(&cnt[dst[e] >> DLO_BITS], 1);
    }
    __syncthreads();
    for (int i = threadIdx.x; i < NB; i += 256)
        if (cnt[i]) atomicAdd(&bcnt[i], cnt[i]);
}

// ---------------- exclusive scan over NB (<=1024) buckets ---------------------
__global__ __launch_bounds__(1024) void scan_kernel(
    const int* __restrict__ bcnt, int* __restrict__ bbase,
    int* __restrict__ bcur, int NB)
{
    __shared__ int s[1024];
    int t = threadIdx.x;
    int v = (t < NB) ? bcnt[t] : 0;
    s[t] = v; __syncthreads();
    for (int off = 1; off < 1024; off <<= 1) {
        int u = (t >= off) ? s[t - off] : 0;
        __syncthreads();
        s[t] += u;
        __syncthreads();
    }
    if (t < NB) { int b = s[t] - v; bbase[t] = b; bcur[t] = b; }
}

// ---------------- bucketed scatter (runs per (block,bucket)) ------------------
__global__ __launch_bounds__(256) void bscatter_kernel(
    const int* __restrict__ src, const int* __restrict__ dst,
    const int* __restrict__ et, int* __restrict__ bcur,
    unsigned* __restrict__ eidx1, int E, int NB)
{
    __shared__ int cnt[1024];
    __shared__ int bbs[1024];
    int tid = threadIdx.x;
    for (int i = tid; i < NB; i += 256) cnt[i] = 0;
    __syncthreads();
    int base = blockIdx.x * SCAT_Q;
    int lim = E - base; if (lim > SCAT_Q) lim = SCAT_Q;
    for (int i = tid; i < lim; i += 256)
        atomicAdd(&cnt[dst[base + i] >> DLO_BITS], 1);
    __syncthreads();
    for (int i = tid; i < NB; i += 256) {
        int c = cnt[i];
        bbs[i] = c ? atomicAdd(&bcur[i], c) : 0;
    }
    __syncthreads();
    for (int i = tid; i < NB; i += 256) cnt[i] = 0;
    __syncthreads();
    for (int i = tid; i < lim; i += 256) {
        int e = base + i;
        int d = dst[e];
        int bk = d >> DLO_BITS;
        int p = bbs[bk] + atomicAdd(&cnt[bk], 1);
        eidx1[p] = (unsigned)src[e] | ((unsigned)et[e] << 17)
                 | ((unsigned)(d & DLO_MASK) << 19);
    }
}

// ---------------- per-bucket counting sort -> exact node CSR ------------------
__global__ __launch_bounds__(256) void bucket_sort_kernel(
    const unsigned* __restrict__ eidx1, const int* __restrict__ bbase,
    const int* __restrict__ bcnt, unsigned* __restrict__ eidx2,
    int* __restrict__ rp, int* __restrict__ rend, int N)
{
    __shared__ int c128[128], excl[128], w[128];
    int tid = threadIdx.x, b = blockIdx.x;
    int gbase = bbase[b], cnt = bcnt[b], n0 = b << DLO_BITS;
    if (tid < 128) c128[tid] = 0;
    __syncthreads();
    for (int k = tid; k < cnt; k += 256)
        atomicAdd(&c128[(eidx1[gbase + k] >> 19) & DLO_MASK], 1);
    __syncthreads();
    if (tid < 128) w[tid] = c128[tid];
    __syncthreads();
    for (int off = 1; off < 128; off <<= 1) {
        int u = (tid < 128 && tid >= off) ? w[tid - off] : 0;
        __syncthreads();
        if (tid < 128) w[tid] += u;
        __syncthreads();
    }
    if (tid < 128) {
        excl[tid] = w[tid] - c128[tid];
        int n = n0 + tid;
        if (n < N) { rp[n] = gbase + excl[tid]; rend[n] = gbase + excl[tid] + c128[tid]; }
        c128[tid] = 0;
    }
    __syncthreads();
    for (int k = tid; k < cnt; k += 256) {
        unsigned pk = eidx1[gbase + k];
        int dlo = (pk >> 19) & DLO_MASK;
        int p = excl[dlo] + atomicAdd(&c128[dlo], 1);
        eidx2[gbase + p] = pk;
    }
}

// ---------------- dense layer-1 v3: weights-only LDS, x via L1 broadcast ------
// builds W on the fly (prep_w1 fused): sW[m] = sum_b comp[m,b]*basis1[b] (m<3), loop1 (m=3)
// hrel[r][n][:] = x@W[r]; agg[n][:] = x@loop1 + bias
__global__ __launch_bounds__(256, 4) void dense_kernel(
    const float* __restrict__ x,
    const float* __restrict__ basis1,   // [2][64][32]
    const float* __restrict__ loop1,    // [64][32]
    const float* __restrict__ w_comp,   // [4][3][2]; layer-0 slice used
    const float* __restrict__ bias_l,   // [32]
    float* __restrict__ hrel,           // [3][N][32]
    float* __restrict__ agg,            // [N][32]
    int N)
{
    __shared__ float sW[4 * 2048];      // [4][64][32], 32 KB (only LDS use)
    const int tid = threadIdx.x;
    for (int i = tid; i < 4 * 2048; i += 256) {
        int m = i >> 11, io = i & 2047;
        float v;
        if (m < 3) v = w_comp[m * 2] * basis1[io] + w_comp[m * 2 + 1] * basis1[2048 + io];
        else       v = loop1[io];
        sW[i] = v;
    }
    __syncthreads();

    const int m  = tid >> 6;       // wave id = which matrix (0..2 rel, 3 loop)
    const int l  = tid & 63;
    const int ow = l & 7;          // output quad: cols ow*4 .. ow*4+3
    const int ng = l >> 3;         // node sub-id: nodes j*8 + ng, j=0..7
    const int nb = blockIdx.x * 64;

    // per-j row pointers, clamped for the partial last block (stores are guarded)
    const float* xr[8];
    #pragma unroll
    for (int j = 0; j < 8; ++j) {
        int gn = nb + j * 8 + ng;
        if (gn > N - 1) gn = N - 1;
        xr[j] = x + (size_t)gn * 64;
    }

    float acc[8][4];
    #pragma unroll
    for (int j = 0; j < 8; ++j)
        #pragma unroll
        for (int k = 0; k < 4; ++k) acc[j][k] = 0.0f;

    const float* wb = &sW[m * 2048 + ow * 4];
    #pragma unroll 2
    for (int i = 0; i < 64; i += 4) {
        float4 wv0 = *(const float4*)(wb + (i + 0) * 32);
        float4 wv1 = *(const float4*)(wb + (i + 1) * 32);
        float4 wv2 = *(const float4*)(wb + (i + 2) * 32);
        float4 wv3 = *(const float4*)(wb + (i + 3) * 32);
        #pragma unroll
        for (int j = 0; j < 8; ++j) {
            float4 hv = *(const float4*)(xr[j] + i);
            acc[j][0] += hv.x * wv0.x + hv.y * wv1.x + hv.z * wv2.x + hv.w * wv3.x;
            acc[j][1] += hv.x * wv0.y + hv.y * wv1.y + hv.z * wv2.y + hv.w * wv3.y;
            acc[j][2] += hv.x * wv0.z + hv.y * wv1.z + hv.z * wv2.z + hv.w * wv3.z;
            acc[j][3] += hv.x * wv0.w + hv.y * wv1.w + hv.z * wv2.w + hv.w * wv3.w;
        }
    }

    if (m < 3) {
        #pragma unroll
        for (int j = 0; j < 8; ++j) {
            int n = nb + j * 8 + ng;
            if (n < N)
                *(float4*)&hrel[((size_t)m * N + n) * 32 + ow * 4] =
                    make_float4(acc[j][0], acc[j][1], acc[j][2], acc[j][3]);
        }
    } else {
        float4 bb = *(const float4*)&bias_l[ow * 4];
        #pragma unroll
        for (int j = 0; j < 8; ++j) {
            int n = nb + j * 8 + ng;
            if (n < N)
                *(float4*)&agg[(size_t)n * 32 + ow * 4] =
                    make_float4(acc[j][0] + bb.x, acc[j][1] + bb.y,
                                acc[j][2] + bb.z, acc[j][3] + bb.w);
        }
    }
}

// ------- layer-1 gather: feat[n][j] = tanh(agg[n][j] + sum hrel[et][src][j]) --
__global__ __launch_bounds__(256) void gather1_kernel(
    const unsigned* __restrict__ eidx, const int* __restrict__ rp,
    const int* __restrict__ rend, const float* __restrict__ hrel,
    const float* __restrict__ agg, float* __restrict__ feat, int N)
{
    int tid = blockIdx.x * 256 + threadIdx.x;
    int n = tid >> 3;
    if (n >= N) return;
    int c = (tid & 7) << 2;
    int base = rp[n], cnt = rend[n] - base;
    const float4 bv = *(const float4*)&agg[(size_t)n * 32 + c];
    float a0[4] = {bv.x, bv.y, bv.z, bv.w};
    float a1[4] = {0, 0, 0, 0}, a2[4] = {0, 0, 0, 0}, a3[4] = {0, 0, 0, 0};
    int k = 0;
    for (; k + 4 <= cnt; k += 4) {
        unsigned p0 = eidx[base + k + 0], p1 = eidx[base + k + 1];
        unsigned p2 = eidx[base + k + 2], p3 = eidx[base + k + 3];
        float4 v0 = *(const float4*)&hrel[(((size_t)((p0 >> 17) & 3)) * N + (p0 & 0x1FFFF)) * 32 + c];
        float4 v1 = *(const float4*)&hrel[(((size_t)((p1 >> 17) & 3)) * N + (p1 & 0x1FFFF)) * 32 + c];
        float4 v2 = *(const float4*)&hrel[(((size_t)((p2 >> 17) & 3)) * N + (p2 & 0x1FFFF)) * 32 + c];
        float4 v3 = *(const float4*)&hrel[(((size_t)((p3 >> 17) & 3)) * N + (p3 & 0x1FFFF)) * 32 + c];
        a0[0] += v0.x; a0[1] += v0.y; a0[2] += v0.z; a0[3] += v0.w;
        a1[0] += v1.x; a1[1] += v1.y; a1[2] += v1.z; a1[3] += v1.w;
        a2[0] += v2.x; a2[1] += v2.y; a2[2] += v2.z; a2[3] += v2.w;
        a3[0] += v3.x; a3[1] += v3.y; a3[2] += v3.z; a3[3] += v3.w;
    }
    for (; k < cnt; ++k) {
        unsigned p = eidx[base + k];
        float4 v = *(const float4*)&hrel[(((size_t)((p >> 17) & 3)) * N + (p & 0x1FFFF)) * 32 + c];
        a0[0] += v.x; a0[1] += v.y; a0[2] += v.z; a0[3] += v.w;
    }
    float r0 = a0[0] + a1[0] + a2[0] + a3[0];
    float r1 = a0[1] + a1[1] + a2[1] + a3[1];
    float r2 = a0[2] + a1[2] + a2[2] + a3[2];
    float r3 = a0[3] + a1[3] + a2[3] + a3[3];
    float4* out = (float4*)&feat[(size_t)n * 128 + c];
    *out = make_float4(tanhf(r0), tanhf(r1), tanhf(r2), tanhf(r3));
}

// ------- fused layers 2-4: T_b[n] = sum_e comp[r,b]*h[src]; out = tanh(...) ---
__global__ __launch_bounds__(256) void fused_layer_kernel(
    const unsigned* __restrict__ eidx, const int* __restrict__ rp,
    const int* __restrict__ rend,
    const float* __restrict__ basis_b,  // [2][32][32]
    const float* __restrict__ loop_w,   // [32][32]
    const float* __restrict__ bias_l,   // [32]
    const float* __restrict__ comp,     // [3][2]
    const float* __restrict__ feat_in,  // feat + (l-1)*32, stride 128
    float* __restrict__ feat_out,       // feat + l*32,     stride 128
    int N)
{
    __shared__ float sB0[1024], sB1[1024], sL[1024];
    __shared__ float sT0[32 * 36], sT1[32 * 36], sH[32 * 36];
    const int tid = threadIdx.x;
    for (int i = tid; i < 1024; i += 256) {
        sB0[i] = basis_b[i];
        sB1[i] = basis_b[1024 + i];
        sL[i]  = loop_w[i];
    }
    const float cc0r0 = comp[0], cc1r0 = comp[1];
    const float cc0r1 = comp[2], cc1r1 = comp[3];
    const float cc0r2 = comp[4], cc1r2 = comp[5];

    const int nn = tid >> 3, cg = (tid & 7) << 2;
    const int n = blockIdx.x * 32 + nn;

    float4 h4 = *(const float4*)&feat_in[(size_t)n * 128 + cg];
    *(float4*)&sH[nn * 36 + cg] = h4;

    const int base = rp[n], cnt = rend[n] - base;
    float t0a[4] = {0,0,0,0}, t1a[4] = {0,0,0,0};
    float t0b[4] = {0,0,0,0}, t1b[4] = {0,0,0,0};
    int k = 0;
    for (; k + 4 <= cnt; k += 4) {
        unsigned p0 = eidx[base + k + 0], p1 = eidx[base + k + 1];
        unsigned p2 = eidx[base + k + 2], p3 = eidx[base + k + 3];
        int r0 = (p0 >> 17) & 3, r1 = (p1 >> 17) & 3;
        int r2 = (p2 >> 17) & 3, r3 = (p3 >> 17) & 3;
        float4 v0 = *(const float4*)&feat_in[(size_t)(p0 & 0x1FFFF) * 128 + cg];
        float4 v1 = *(const float4*)&feat_in[(size_t)(p1 & 0x1FFFF) * 128 + cg];
        float4 v2 = *(const float4*)&feat_in[(size_t)(p2 & 0x1FFFF) * 128 + cg];
        float4 v3 = *(const float4*)&feat_in[(size_t)(p3 & 0x1FFFF) * 128 + cg];
        float c00 = r0 == 0 ? cc0r0 : (r0 == 1 ? cc0r1 : cc0r2);
        float c10 = r0 == 0 ? cc1r0 : (r0 == 1 ? cc1r1 : cc1r2);
        float c01 = r1 == 0 ? cc0r0 : (r1 == 1 ? cc0r1 : cc0r2);
        float c11 = r1 == 0 ? cc1r0 : (r1 == 1 ? cc1r1 : cc1r2);
        float c02 = r2 == 0 ? cc0r0 : (r2 == 1 ? cc0r1 : cc0r2);
        float c12 = r2 == 0 ? cc1r0 : (r2 == 1 ? cc1r1 : cc1r2);
        float c03 = r3 == 0 ? cc0r0 : (r3 == 1 ? cc0r1 : cc0r2);
        float c13 = r3 == 0 ? cc1r0 : (r3 == 1 ? cc1r1 : cc1r2);
        t0a[0] += c00*v0.x; t0a[1] += c00*v0.y; t0a[2] += c00*v0.z; t0a[3] += c00*v0.w;
        t1a[0] += c10*v0.x; t1a[1] += c10*v0.y; t1a[2] += c10*v0.z; t1a[3] += c10*v0.w;
        t0b[0] += c01*v1.x; t0b[1] += c01*v1.y; t0b[2] += c01*v1.z; t0b[3] += c01*v1.w;
        t1b[0] += c11*v1.x; t1b[1] += c11*v1.y; t1b[2] += c11*v1.z; t1b[3] += c11*v1.w;
        t0a[0] += c02*v2.x; t0a[1] += c02*v2.y; t0a[2] += c02*v2.z; t0a[3] += c02*v2.w;
        t1a[0] += c12*v2.x; t1a[1] += c12*v2.y; t1a[2] += c12*v2.z; t1a[3] += c12*v2.w;
        t0b[0] += c03*v3.x; t0b[1] += c03*v3.y; t0b[2] += c03*v3.z; t0b[3] += c03*v3.w;
        t1b[0] += c13*v3.x; t1b[1] += c13*v3.y; t1b[2] += c13*v3.z; t1b[3] += c13*v3.w;
    }
    for (; k < cnt; ++k) {
        unsigned p = eidx[base + k];
        int r = (p >> 17) & 3;
        float4 v = *(const float4*)&feat_in[(size_t)(p & 0x1FFFF) * 128 + cg];
        float c0 = r == 0 ? cc0r0 : (r == 1 ? cc0r1 : cc0r2);
        float c1 = r == 0 ? cc1r0 : (r == 1 ? cc1r1 : cc1r2);
        t0a[0] += c0*v.x; t0a[1] += c0*v.y; t0a[2] += c0*v.z; t0a[3] += c0*v.w;
        t1a[0] += c1*v.x; t1a[1] += c1*v.y; t1a[2] += c1*v.z; t1a[3] += c1*v.w;
    }
    *(float4*)&sT0[nn * 36 + cg] = make_float4(t0a[0]+t0b[0], t0a[1]+t0b[1],
                                               t0a[2]+t0b[2], t0a[3]+t0b[3]);
    *(float4*)&sT1[nn * 36 + cg] = make_float4(t1a[0]+t1b[0], t1a[1]+t1b[1],
                                               t1a[2]+t1b[2], t1a[3]+t1b[3]);
    __syncthreads();

    float4 bb = *(const float4*)&bias_l[cg];
    float a[4] = {bb.x, bb.y, bb.z, bb.w};
    #pragma unroll 8
    for (int kk = 0; kk < 32; ++kk) {
        float p0 = sT0[nn * 36 + kk];
        float p1 = sT1[nn * 36 + kk];
        float hh = sH[nn * 36 + kk];
        float4 b0 = *(const float4*)&sB0[kk * 32 + cg];
        float4 b1 = *(const float4*)&sB1[kk * 32 + cg];
        float4 lw = *(const float4*)&sL[kk * 32 + cg];
        a[0] += p0 * b0.x + p1 * b1.x + hh * lw.x;
        a[1] += p0 * b0.y + p1 * b1.y + hh * lw.y;
        a[2] += p0 * b0.z + p1 * b1.z + hh * lw.z;
        a[3] += p0 * b0.w + p1 * b1.w + hh * lw.w;
    }
    *(float4*)&feat_out[(size_t)n * 128 + cg] =
        make_float4(tanhf(a[0]), tanhf(a[1]), tanhf(a[2]), tanhf(a[3]));
}

// ------- pooling: node-chunk blocks, run-accumulate, atomic flush ----------
__global__ __launch_bounds__(256) void pool_kernel(
    const float* __restrict__ feat, const int* __restrict__ gid,
    float* __restrict__ pooled, float* __restrict__ cntArr, int N)
{
    int chunk0 = blockIdx.x * 128;
    int ch = threadIdx.x & 127, half = threadIdx.x >> 7;
    int n = chunk0 + half;
    int lim = chunk0 + 128; if (lim > N) lim = N;
    if (n >= lim) return;
    int cur = gid[n];
    float acc = 0.0f; int cc = 0;
    for (; n < lim; n += 2) {
        int g = gid[n];
        if (g != cur) {
            atomicAdd(&pooled[(size_t)cur * 128 + ch], acc);
            if (ch == 0) atomicAdd(&cntArr[cur], (float)cc);
            acc = 0.0f; cc = 0; cur = g;
        }
        acc += feat[(size_t)n * 128 + ch];
        ++cc;
    }
    atomicAdd(&pooled[(size_t)cur * 128 + ch], acc);
    if (ch == 0) atomicAdd(&cntArr[cur], (float)cc);
}

// ---------------- final MLP (divides pooled sums by counts) -------------------
__global__ __launch_bounds__(64) void mlp_kernel(
    const float* __restrict__ pooled, const float* __restrict__ cntArr,
    const float* __restrict__ w1, const float* __restrict__ b1,
    const float* __restrict__ w2, const float* __restrict__ b2,
    float* __restrict__ out)
{
    int g = blockIdx.x;
    int t = threadIdx.x;  // 64
    float inv = 1.0f / fmaxf(cntArr[g], 1.0f);
    float acc = b1[t];
    #pragma unroll 8
    for (int k = 0; k < 128; ++k)
        acc += pooled[(size_t)g * 128 + k] * inv * w1[k * 64 + t];
    float h = fmaxf(acc, 0.0f);
    float p = h * w2[t];
    #pragma unroll
    for (int off = 32; off > 0; off >>= 1) p += __shfl_down(p, off, 64);
    if (t == 0) out[g] = 1.0f / (1.0f + expf(-(p + b2[0])));
}

extern "C" void kernel_launch(void* const* d_in, const int* in_sizes, int n_in,
                              void* d_out, int out_size, void* d_ws, size_t ws_size,
                              hipStream_t stream)
{
    const float* x       = (const float*)d_in[0];
    const float* basis1  = (const float*)d_in[1];
    const float* basis_r = (const float*)d_in[2];
    const float* w_comp  = (const float*)d_in[3];
    const float* loop1   = (const float*)d_in[4];
    const float* loop_r  = (const float*)d_in[5];
    const float* bias    = (const float*)d_in[6];
    const float* lin1_w  = (const float*)d_in[7];
    const float* lin1_b  = (const float*)d_in[8];
    const float* lin2_w  = (const float*)d_in[9];
    const float* lin2_b  = (const float*)d_in[10];
    const int*   src     = (const int*)d_in[11];
    const int*   dst     = (const int*)d_in[12];
    const int*   etype   = (const int*)d_in[13];
    const int*   gid     = (const int*)d_in[14];

    const int N = in_sizes[0] / 64;
    const int E = in_sizes[11];
    const int G = out_size;  // 256
    const int NB = (N + DLO_MASK) >> DLO_BITS;  // 782

    // workspace layout (words):
    // hrel[3*N*32] | agg[N*32] | feat[N*128] | pooled[G*128] | cntArr[G]
    // | bcnt[NB] | bbase[NB] | bcur[NB] | rp[N] | rend[N] | eidx2[E]
    // eidx1 aliases feat (consumed by bucket_sort before gather1 writes feat)
    float* ws      = (float*)d_ws;
    float* hrel    = ws;                          // 3*N*32
    float* agg     = hrel + (size_t)3 * N * 32;   // N*32
    float* feat    = agg + (size_t)N * 32;        // N*128
    float* pooled  = feat + (size_t)N * 128;      // G*128
    float* cntArr  = pooled + (size_t)G * 128;    // G
    int*   bcnt    = (int*)(cntArr + G);          // NB
    int*   bbase   = bcnt + NB;                   // NB
    int*   bcur    = bbase + NB;                  // NB
    int*   rp      = bcur + NB;                   // N
    int*   rend    = rp + N;                      // N
    unsigned* eidx2 = (unsigned*)(rend + N);      // E
    unsigned* eidx1 = (unsigned*)feat;            // alias

    // zero pooled + cntArr + bcnt in one shot (contiguous)
    hipMemsetAsync(pooled, 0, ((size_t)G * 128 + G + NB) * sizeof(float), stream);

    // CSR build: count -> scan -> bucketed scatter -> in-bucket sort
    const int nsb = (E + SCAT_Q - 1) / SCAT_Q;    // 782 blocks
    count_kernel<<<nsb, 256, 0, stream>>>(dst, bcnt, E, NB);
    scan_kernel<<<1, 1024, 0, stream>>>(bcnt, bbase, bcur, NB);
    bscatter_kernel<<<nsb, 256, 0, stream>>>(src, dst, etype, bcur, eidx1, E, NB);
    bucket_sort_kernel<<<NB, 256, 0, stream>>>(eidx1, bbase, bcnt, eidx2, rp, rend, N);

    // layer 1: dense (weight-prep fused; x via L1) + register gather (fused tanh)
    dense_kernel<<<(N + 63) / 64, 256, 0, stream>>>(x, basis1, loop1, w_comp, bias, hrel, agg, N);
    gather1_kernel<<<(N * 8 + 255) / 256, 256, 0, stream>>>(eidx2, rp, rend, hrel, agg, feat, N);

    // layers 2-4: fused comp-weighted gather + in-LDS matmuls + tanh
    for (int l = 1; l < 4; ++l) {
        fused_layer_kernel<<<(N + 31) / 32, 256, 0, stream>>>(
            eidx2, rp, rend,
            basis_r + (size_t)(l - 1) * 2048,
            loop_r + (size_t)(l - 1) * 1024,
            bias + l * 32,
            w_comp + l * 6,
            feat + (l - 1) * 32,
            feat + l * 32,
            N);
    }

    pool_kernel<<<(N + 127) / 128, 256, 0, stream>>>(feat, gid, pooled, cntArr, N);
    mlp_kernel<<<G, 64, 0, stream>>>(pooled, cntArr, lin1_w, lin1_b, lin2_w, lin2_b, (float*)d_out);
}

// Round 3
// 343.689 us; speedup vs baseline: 1.3707x; 1.0928x over previous
//
#include <hip/hip_runtime.h>
#include <cstdint>
#include <cmath>

// Problem constants: N=100000, IN=64, HID=32, R=3, B=2, E=1600000, G=256, 4 layers
// CSR build: bucketed (write-locality) build, SCAT_Q=2048 for occupancy.
// Buckets: bucket = dst >> 7 (128 nodes), NB = ceil(N/128) = 782
#define DLO_BITS 7
#define DLO_MASK 127
#define SCAT_Q 2048

// ---------------- bucket count ----------------
__global__ __launch_bounds__(256) void count_kernel(
    const int* __restrict__ dst, int* __restrict__ bcnt, int E, int NB)
{
    __shared__ int cnt[1024];
    for (int i = threadIdx.x; i < NB; i += 256) cnt[i] = 0;
    __syncthreads();
    int base = blockIdx.x * SCAT_Q;
    #pragma unroll
    for (int i = 0; i < SCAT_Q / 256; ++i) {
        int e = base + i * 256 + threadIdx.x;
        if (e < E) atomicAdd(&cnt[dst[e] >> DLO_BITS], 1);
    }
    __syncthreads();
    for (int i = threadIdx.x; i < NB; i += 256)
        if (cnt[i]) atomicAdd(&bcnt[i], cnt[i]);
}

// ---------------- exclusive scan over NB (<=1024) buckets ---------------------
__global__ __launch_bounds__(1024) void scan_kernel(
    const int* __restrict__ bcnt, int* __restrict__ bbase,
    int* __restrict__ bcur, int NB)
{
    __shared__ int s[1024];
    int t = threadIdx.x;
    int v = (t < NB) ? bcnt[t] : 0;
    s[t] = v; __syncthreads();
    for (int off = 1; off < 1024; off <<= 1) {
        int u = (t >= off) ? s[t - off] : 0;
        __syncthreads();
        s[t] += u;
        __syncthreads();
    }
    if (t < NB) { int b = s[t] - v; bbase[t] = b; bcur[t] = b; }
}

// ---------------- bucketed scatter (runs per (block,bucket)) ------------------
__global__ __launch_bounds__(256) void bscatter_kernel(
    const int* __restrict__ src, const int* __restrict__ dst,
    const int* __restrict__ et, int* __restrict__ bcur,
    unsigned* __restrict__ eidx1, int E, int NB)
{
    __shared__ int cnt[1024];
    __shared__ int bbs[1024];
    int tid = threadIdx.x;
    for (int i = tid; i < NB; i += 256) cnt[i] = 0;
    __syncthreads();
    int base = blockIdx.x * SCAT_Q;
    int lim = E - base; if (lim > SCAT_Q) lim = SCAT_Q;
    for (int i = tid; i < lim; i += 256)
        atomicAdd(&cnt[dst[base + i] >> DLO_BITS], 1);
    __syncthreads();
    for (int i = tid; i < NB; i += 256) {
        int c = cnt[i];
        bbs[i] = c ? atomicAdd(&bcur[i], c) : 0;
    }
    __syncthreads();
    for (int i = tid; i < NB; i += 256) cnt[i] = 0;
    __syncthreads();
    for (int i = tid; i < lim; i += 256) {
        int e = base + i;
        int d = dst[e];
        int bk = d >> DLO_BITS;
        int p = bbs[bk] + atomicAdd(&cnt[bk], 1);
        eidx1[p] = (unsigned)src[e] | ((unsigned)et[e] << 17)
                 | ((unsigned)(d & DLO_MASK) << 19);
    }
}

// ---------------- per-bucket counting sort -> exact node CSR ------------------
__global__ __launch_bounds__(256) void bucket_sort_kernel(
    const unsigned* __restrict__ eidx1, const int* __restrict__ bbase,
    const int* __restrict__ bcnt, unsigned* __restrict__ eidx2,
    int* __restrict__ rp, int* __restrict__ rend, int N)
{
    __shared__ int c128[128], excl[128], w[128];
    int tid = threadIdx.x, b = blockIdx.x;
    int gbase = bbase[b], cnt = bcnt[b], n0 = b << DLO_BITS;
    if (tid < 128) c128[tid] = 0;
    __syncthreads();
    for (int k = tid; k < cnt; k += 256)
        atomicAdd(&c128[(eidx1[gbase + k] >> 19) & DLO_MASK], 1);
    __syncthreads();
    if (tid < 128) w[tid] = c128[tid];
    __syncthreads();
    for (int off = 1; off < 128; off <<= 1) {
        int u = (tid < 128 && tid >= off) ? w[tid - off] : 0;
        __syncthreads();
        if (tid < 128) w[tid] += u;
        __syncthreads();
    }
    if (tid < 128) {
        excl[tid] = w[tid] - c128[tid];
        int n = n0 + tid;
        if (n < N) { rp[n] = gbase + excl[tid]; rend[n] = gbase + excl[tid] + c128[tid]; }
        c128[tid] = 0;
    }
    __syncthreads();
    for (int k = tid; k < cnt; k += 256) {
        unsigned pk = eidx1[gbase + k];
        int dlo = (pk >> 19) & DLO_MASK;
        int p = excl[dlo] + atomicAdd(&c128[dlo], 1);
        eidx2[gbase + p] = pk;
    }
}

// ---------------- dense layer-1 (round-0 structure + fused weight prep) -------
// sW[m] = sum_b comp[m,b]*basis1[b] (m<3), loop1 (m=3); x staged in LDS.
// hrel[r][n][:] = x@W[r]; agg[n][:] = x@loop1 + bias
__global__ __launch_bounds__(256) void dense_kernel(
    const float* __restrict__ x,
    const float* __restrict__ basis1,   // [2][64][32]
    const float* __restrict__ loop1,    // [64][32]
    const float* __restrict__ w_comp,   // [4][3][2]; layer-0 slice used
    const float* __restrict__ bias_l,   // [32]
    float* __restrict__ hrel,           // [3][N][32]
    float* __restrict__ agg,            // [N][32]
    int N)
{
    __shared__ float sW[4 * 2048];     // [4][64][32], 32 KB
    __shared__ float sH[64 * 68];      // [64 nodes][stride 68], 17 KB
    const int tid = threadIdx.x;
    for (int i = tid; i < 4 * 2048; i += 256) {
        int m = i >> 11, io = i & 2047;
        float v;
        if (m < 3) v = w_comp[m * 2] * basis1[io] + w_comp[m * 2 + 1] * basis1[2048 + io];
        else       v = loop1[io];
        sW[i] = v;
    }
    const int nb = blockIdx.x * 64;
    for (int idx = tid; idx < 64 * 64; idx += 256) {
        int n = idx >> 6, i = idx & 63;
        int gn = nb + n;
        sH[n * 68 + i] = (gn < N) ? x[(size_t)gn * 64 + i] : 0.0f;
    }
    __syncthreads();

    const int m  = tid >> 6;       // wave id = which matrix (0..2 rel, 3 loop)
    const int l  = tid & 63;
    const int ow = l & 7;          // output quad: cols ow*4 .. ow*4+3
    const int ng = l >> 3;         // node sub-id: nodes j*8 + ng, j=0..7

    float acc[8][4];
    #pragma unroll
    for (int j = 0; j < 8; ++j)
        #pragma unroll
        for (int k = 0; k < 4; ++k) acc[j][k] = 0.0f;

    const float* wb = &sW[m * 2048 + ow * 4];
    #pragma unroll 2
    for (int i = 0; i < 64; i += 4) {
        float4 wv0 = *(const float4*)(wb + (i + 0) * 32);
        float4 wv1 = *(const float4*)(wb + (i + 1) * 32);
        float4 wv2 = *(const float4*)(wb + (i + 2) * 32);
        float4 wv3 = *(const float4*)(wb + (i + 3) * 32);
        #pragma unroll
        for (int j = 0; j < 8; ++j) {
            float4 hv = *(const float4*)&sH[(j * 8 + ng) * 68 + i];
            acc[j][0] += hv.x * wv0.x + hv.y * wv1.x + hv.z * wv2.x + hv.w * wv3.x;
            acc[j][1] += hv.x * wv0.y + hv.y * wv1.y + hv.z * wv2.y + hv.w * wv3.y;
            acc[j][2] += hv.x * wv0.z + hv.y * wv1.z + hv.z * wv2.z + hv.w * wv3.z;
            acc[j][3] += hv.x * wv0.w + hv.y * wv1.w + hv.z * wv2.w + hv.w * wv3.w;
        }
    }

    if (m < 3) {
        #pragma unroll
        for (int j = 0; j < 8; ++j) {
            int n = nb + j * 8 + ng;
            if (n < N)
                *(float4*)&hrel[((size_t)m * N + n) * 32 + ow * 4] =
                    make_float4(acc[j][0], acc[j][1], acc[j][2], acc[j][3]);
        }
    } else {
        float4 bb = *(const float4*)&bias_l[ow * 4];
        #pragma unroll
        for (int j = 0; j < 8; ++j) {
            int n = nb + j * 8 + ng;
            if (n < N)
                *(float4*)&agg[(size_t)n * 32 + ow * 4] =
                    make_float4(acc[j][0] + bb.x, acc[j][1] + bb.y,
                                acc[j][2] + bb.z, acc[j][3] + bb.w);
        }
    }
}

// ------- layer-1 gather: feat[n][j] = tanh(agg[n][j] + sum hrel[et][src][j]) --
__global__ __launch_bounds__(256) void gather1_kernel(
    const unsigned* __restrict__ eidx, const int* __restrict__ rp,
    const int* __restrict__ rend, const float* __restrict__ hrel,
    const float* __restrict__ agg, float* __restrict__ feat, int N)
{
    int tid = blockIdx.x * 256 + threadIdx.x;
    int n = tid >> 3;
    if (n >= N) return;
    int c = (tid & 7) << 2;
    int base = rp[n], cnt = rend[n] - base;
    const float4 bv = *(const float4*)&agg[(size_t)n * 32 + c];
    float a0[4] = {bv.x, bv.y, bv.z, bv.w};
    float a1[4] = {0, 0, 0, 0}, a2[4] = {0, 0, 0, 0}, a3[4] = {0, 0, 0, 0};
    int k = 0;
    for (; k + 4 <= cnt; k += 4) {
        unsigned p0 = eidx[base + k + 0], p1 = eidx[base + k + 1];
        unsigned p2 = eidx[base + k + 2], p3 = eidx[base + k + 3];
        float4 v0 = *(const float4*)&hrel[(((size_t)((p0 >> 17) & 3)) * N + (p0 & 0x1FFFF)) * 32 + c];
        float4 v1 = *(const float4*)&hrel[(((size_t)((p1 >> 17) & 3)) * N + (p1 & 0x1FFFF)) * 32 + c];
        float4 v2 = *(const float4*)&hrel[(((size_t)((p2 >> 17) & 3)) * N + (p2 & 0x1FFFF)) * 32 + c];
        float4 v3 = *(const float4*)&hrel[(((size_t)((p3 >> 17) & 3)) * N + (p3 & 0x1FFFF)) * 32 + c];
        a0[0] += v0.x; a0[1] += v0.y; a0[2] += v0.z; a0[3] += v0.w;
        a1[0] += v1.x; a1[1] += v1.y; a1[2] += v1.z; a1[3] += v1.w;
        a2[0] += v2.x; a2[1] += v2.y; a2[2] += v2.z; a2[3] += v2.w;
        a3[0] += v3.x; a3[1] += v3.y; a3[2] += v3.z; a3[3] += v3.w;
    }
    for (; k < cnt; ++k) {
        unsigned p = eidx[base + k];
        float4 v = *(const float4*)&hrel[(((size_t)((p >> 17) & 3)) * N + (p & 0x1FFFF)) * 32 + c];
        a0[0] += v.x; a0[1] += v.y; a0[2] += v.z; a0[3] += v.w;
    }
    float r0 = a0[0] + a1[0] + a2[0] + a3[0];
    float r1 = a0[1] + a1[1] + a2[1] + a3[1];
    float r2 = a0[2] + a1[2] + a2[2] + a3[2];
    float r3 = a0[3] + a1[3] + a2[3] + a3[3];
    float4* out = (float4*)&feat[(size_t)n * 128 + c];
    *out = make_float4(tanhf(r0), tanhf(r1), tanhf(r2), tanhf(r3));
}

// ------- fused layers 2-4: T_b[n] = sum_e comp[r,b]*h[src]; out = tanh(...) ---
__global__ __launch_bounds__(256) void fused_layer_kernel(
    const unsigned* __restrict__ eidx, const int* __restrict__ rp,
    const int* __restrict__ rend,
    const float* __restrict__ basis_b,  // [2][32][32]
    const float* __restrict__ loop_w,   // [32][32]
    const float* __restrict__ bias_l,   // [32]
    const float* __restrict__ comp,     // [3][2]
    const float* __restrict__ feat_in,  // feat + (l-1)*32, stride 128
    float* __restrict__ feat_out,       // feat + l*32,     stride 128
    int N)
{
    __shared__ float sB0[1024], sB1[1024], sL[1024];
    __shared__ float sT0[32 * 36], sT1[32 * 36], sH[32 * 36];
    const int tid = threadIdx.x;
    for (int i = tid; i < 1024; i += 256) {
        sB0[i] = basis_b[i];
        sB1[i] = basis_b[1024 + i];
        sL[i]  = loop_w[i];
    }
    const float cc0r0 = comp[0], cc1r0 = comp[1];
    const float cc0r1 = comp[2], cc1r1 = comp[3];
    const float cc0r2 = comp[4], cc1r2 = comp[5];

    const int nn = tid >> 3, cg = (tid & 7) << 2;
    const int n = blockIdx.x * 32 + nn;

    float4 h4 = *(const float4*)&feat_in[(size_t)n * 128 + cg];
    *(float4*)&sH[nn * 36 + cg] = h4;

    const int base = rp[n], cnt = rend[n] - base;
    float t0a[4] = {0,0,0,0}, t1a[4] = {0,0,0,0};
    float t0b[4] = {0,0,0,0}, t1b[4] = {0,0,0,0};
    int k = 0;
    for (; k + 4 <= cnt; k += 4) {
        unsigned p0 = eidx[base + k + 0], p1 = eidx[base + k + 1];
        unsigned p2 = eidx[base + k + 2], p3 = eidx[base + k + 3];
        int r0 = (p0 >> 17) & 3, r1 = (p1 >> 17) & 3;
        int r2 = (p2 >> 17) & 3, r3 = (p3 >> 17) & 3;
        float4 v0 = *(const float4*)&feat_in[(size_t)(p0 & 0x1FFFF) * 128 + cg];
        float4 v1 = *(const float4*)&feat_in[(size_t)(p1 & 0x1FFFF) * 128 + cg];
        float4 v2 = *(const float4*)&feat_in[(size_t)(p2 & 0x1FFFF) * 128 + cg];
        float4 v3 = *(const float4*)&feat_in[(size_t)(p3 & 0x1FFFF) * 128 + cg];
        float c00 = r0 == 0 ? cc0r0 : (r0 == 1 ? cc0r1 : cc0r2);
        float c10 = r0 == 0 ? cc1r0 : (r0 == 1 ? cc1r1 : cc1r2);
        float c01 = r1 == 0 ? cc0r0 : (r1 == 1 ? cc0r1 : cc0r2);
        float c11 = r1 == 0 ? cc1r0 : (r1 == 1 ? cc1r1 : cc1r2);
        float c02 = r2 == 0 ? cc0r0 : (r2 == 1 ? cc0r1 : cc0r2);
        float c12 = r2 == 0 ? cc1r0 : (r2 == 1 ? cc1r1 : cc1r2);
        float c03 = r3 == 0 ? cc0r0 : (r3 == 1 ? cc0r1 : cc0r2);
        float c13 = r3 == 0 ? cc1r0 : (r3 == 1 ? cc1r1 : cc1r2);
        t0a[0] += c00*v0.x; t0a[1] += c00*v0.y; t0a[2] += c00*v0.z; t0a[3] += c00*v0.w;
        t1a[0] += c10*v0.x; t1a[1] += c10*v0.y; t1a[2] += c10*v0.z; t1a[3] += c10*v0.w;
        t0b[0] += c01*v1.x; t0b[1] += c01*v1.y; t0b[2] += c01*v1.z; t0b[3] += c01*v1.w;
        t1b[0] += c11*v1.x; t1b[1] += c11*v1.y; t1b[2] += c11*v1.z; t1b[3] += c11*v1.w;
        t0a[0] += c02*v2.x; t0a[1] += c02*v2.y; t0a[2] += c02*v2.z; t0a[3] += c02*v2.w;
        t1a[0] += c12*v2.x; t1a[1] += c12*v2.y; t1a[2] += c12*v2.z; t1a[3] += c12*v2.w;
        t0b[0] += c03*v3.x; t0b[1] += c03*v3.y; t0b[2] += c03*v3.z; t0b[3] += c03*v3.w;
        t1b[0] += c13*v3.x; t1b[1] += c13*v3.y; t1b[2] += c13*v3.z; t1b[3] += c13*v3.w;
    }
    for (; k < cnt; ++k) {
        unsigned p = eidx[base + k];
        int r = (p >> 17) & 3;
        float4 v = *(const float4*)&feat_in[(size_t)(p & 0x1FFFF) * 128 + cg];
        float c0 = r == 0 ? cc0r0 : (r == 1 ? cc0r1 : cc0r2);
        float c1 = r == 0 ? cc1r0 : (r == 1 ? cc1r1 : cc1r2);
        t0a[0] += c0*v.x; t0a[1] += c0*v.y; t0a[2] += c0*v.z; t0a[3] += c0*v.w;
        t1a[0] += c1*v.x; t1a[1] += c1*v.y; t1a[2] += c1*v.z; t1a[3] += c1*v.w;
    }
    *(float4*)&sT0[nn * 36 + cg] = make_float4(t0a[0]+t0b[0], t0a[1]+t0b[1],
                                               t0a[2]+t0b[2], t0a[3]+t0b[3]);
    *(float4*)&sT1[nn * 36 + cg] = make_float4(t1a[0]+t1b[0], t1a[1]+t1b[1],
                                               t1a[2]+t1b[2], t1a[3]+t1b[3]);
    __syncthreads();

    float4 bb = *(const float4*)&bias_l[cg];
    float a[4] = {bb.x, bb.y, bb.z, bb.w};
    #pragma unroll 8
    for (int kk = 0; kk < 32; ++kk) {
        float p0 = sT0[nn * 36 + kk];
        float p1 = sT1[nn * 36 + kk];
        float hh = sH[nn * 36 + kk];
        float4 b0 = *(const float4*)&sB0[kk * 32 + cg];
        float4 b1 = *(const float4*)&sB1[kk * 32 + cg];
        float4 lw = *(const float4*)&sL[kk * 32 + cg];
        a[0] += p0 * b0.x + p1 * b1.x + hh * lw.x;
        a[1] += p0 * b0.y + p1 * b1.y + hh * lw.y;
        a[2] += p0 * b0.z + p1 * b1.z + hh * lw.z;
        a[3] += p0 * b0.w + p1 * b1.w + hh * lw.w;
    }
    *(float4*)&feat_out[(size_t)n * 128 + cg] =
        make_float4(tanhf(a[0]), tanhf(a[1]), tanhf(a[2]), tanhf(a[3]));
}

// ------- pooling: node-chunk blocks, run-accumulate, atomic flush ----------
__global__ __launch_bounds__(256) void pool_kernel(
    const float* __restrict__ feat, const int* __restrict__ gid,
    float* __restrict__ pooled, float* __restrict__ cntArr, int N)
{
    int chunk0 = blockIdx.x * 128;
    int ch = threadIdx.x & 127, half = threadIdx.x >> 7;
    int n = chunk0 + half;
    int lim = chunk0 + 128; if (lim > N) lim = N;
    if (n >= lim) return;
    int cur = gid[n];
    float acc = 0.0f; int cc = 0;
    for (; n < lim; n += 2) {
        int g = gid[n];
        if (g != cur) {
            atomicAdd(&pooled[(size_t)cur * 128 + ch], acc);
            if (ch == 0) atomicAdd(&cntArr[cur], (float)cc);
            acc = 0.0f; cc = 0; cur = g;
        }
        acc += feat[(size_t)n * 128 + ch];
        ++cc;
    }
    atomicAdd(&pooled[(size_t)cur * 128 + ch], acc);
    if (ch == 0) atomicAdd(&cntArr[cur], (float)cc);
}

// ---------------- final MLP (divides pooled sums by counts) -------------------
__global__ __launch_bounds__(64) void mlp_kernel(
    const float* __restrict__ pooled, const float* __restrict__ cntArr,
    const float* __restrict__ w1, const float* __restrict__ b1,
    const float* __restrict__ w2, const float* __restrict__ b2,
    float* __restrict__ out)
{
    int g = blockIdx.x;
    int t = threadIdx.x;  // 64
    float inv = 1.0f / fmaxf(cntArr[g], 1.0f);
    float acc = b1[t];
    #pragma unroll 8
    for (int k = 0; k < 128; ++k)
        acc += pooled[(size_t)g * 128 + k] * inv * w1[k * 64 + t];
    float h = fmaxf(acc, 0.0f);
    float p = h * w2[t];
    #pragma unroll
    for (int off = 32; off > 0; off >>= 1) p += __shfl_down(p, off, 64);
    if (t == 0) out[g] = 1.0f / (1.0f + expf(-(p + b2[0])));
}

extern "C" void kernel_launch(void* const* d_in, const int* in_sizes, int n_in,
                              void* d_out, int out_size, void* d_ws, size_t ws_size,
                              hipStream_t stream)
{
    const float* x       = (const float*)d_in[0];
    const float* basis1  = (const float*)d_in[1];
    const float* basis_r = (const float*)d_in[2];
    const float* w_comp  = (const float*)d_in[3];
    const float* loop1   = (const float*)d_in[4];
    const float* loop_r  = (const float*)d_in[5];
    const float* bias    = (const float*)d_in[6];
    const float* lin1_w  = (const float*)d_in[7];
    const float* lin1_b  = (const float*)d_in[8];
    const float* lin2_w  = (const float*)d_in[9];
    const float* lin2_b  = (const float*)d_in[10];
    const int*   src     = (const int*)d_in[11];
    const int*   dst     = (const int*)d_in[12];
    const int*   etype   = (const int*)d_in[13];
    const int*   gid     = (const int*)d_in[14];

    const int N = in_sizes[0] / 64;
    const int E = in_sizes[11];
    const int G = out_size;  // 256
    const int NB = (N + DLO_MASK) >> DLO_BITS;  // 782

    // workspace layout (words):
    // hrel[3*N*32] | agg[N*32] | feat[N*128] | pooled[G*128] | cntArr[G]
    // | bcnt[NB] | bbase[NB] | bcur[NB] | rp[N] | rend[N] | eidx2[E]
    // eidx1 aliases feat (consumed by bucket_sort before gather1 writes feat)
    float* ws      = (float*)d_ws;
    float* hrel    = ws;                          // 3*N*32
    float* agg     = hrel + (size_t)3 * N * 32;   // N*32
    float* feat    = agg + (size_t)N * 32;        // N*128
    float* pooled  = feat + (size_t)N * 128;      // G*128
    float* cntArr  = pooled + (size_t)G * 128;    // G
    int*   bcnt    = (int*)(cntArr + G);          // NB
    int*   bbase   = bcnt + NB;                   // NB
    int*   bcur    = bbase + NB;                  // NB
    int*   rp      = bcur + NB;                   // N
    int*   rend    = rp + N;                      // N
    unsigned* eidx2 = (unsigned*)(rend + N);      // E
    unsigned* eidx1 = (unsigned*)feat;            // alias

    // zero pooled + cntArr + bcnt in one shot (contiguous)
    hipMemsetAsync(pooled, 0, ((size_t)G * 128 + G + NB) * sizeof(float), stream);

    // CSR build: count -> scan -> bucketed scatter -> in-bucket sort
    const int nsb = (E + SCAT_Q - 1) / SCAT_Q;    // 782 blocks
    count_kernel<<<nsb, 256, 0, stream>>>(dst, bcnt, E, NB);
    scan_kernel<<<1, 1024, 0, stream>>>(bcnt, bbase, bcur, NB);
    bscatter_kernel<<<nsb, 256, 0, stream>>>(src, dst, etype, bcur, eidx1, E, NB);
    bucket_sort_kernel<<<NB, 256, 0, stream>>>(eidx1, bbase, bcnt, eidx2, rp, rend, N);

    // layer 1: dense (staged x, fused weight prep) + register gather (fused tanh)
    dense_kernel<<<(N + 63) / 64, 256, 0, stream>>>(x, basis1, loop1, w_comp, bias, hrel, agg, N);
    gather1_kernel<<<(N * 8 + 255) / 256, 256, 0, stream>>>(eidx2, rp, rend, hrel, agg, feat, N);

    // layers 2-4: fused comp-weighted gather + in-LDS matmuls + tanh
    for (int l = 1; l < 4; ++l) {
        fused_layer_kernel<<<(N + 31) / 32, 256, 0, stream>>>(
            eidx2, rp, rend,
            basis_r + (size_t)(l - 1) * 2048,
            loop_r + (size_t)(l - 1) * 1024,
            bias + l * 32,
            w_comp + l * 6,
            feat + (l - 1) * 32,
            feat + l * 32,
            N);
    }

    pool_kernel<<<(N + 127) / 128, 256, 0, stream>>>(feat, gid, pooled, cntArr, N);
    mlp_kernel<<<G, 64, 0, stream>>>(pooled, cntArr, lin1_w, lin1_b, lin2_w, lin2_b, (float*)d_out);
}